// Round 3
// baseline (248.953 us; speedup 1.0000x reference)
//
#include <hip/hip_runtime.h>

#define N_NODES 50000
#define N_EDGES 800000
#define D 64

// ---------- Phase 1: histogram of rows ----------
__global__ __launch_bounds__(256) void hist_kernel(
    const int* __restrict__ rows, int* __restrict__ counts)
{
    int e = blockIdx.x * 256 + threadIdx.x;
    if (e < N_EDGES) atomicAdd(&counts[rows[e]], 1);
}

// ---------- Phase 2: single-block exclusive scan, 2 barriers total ----------
// Each of 1024 threads owns 49 contiguous elements. Wave-level shfl scans.
// Converts counts[] into the cursor array in place; writes offsets[0..N].
#define SCAN_T 1024
#define PER    49   // ceil(50000/1024)

__global__ __launch_bounds__(1024) void scan_kernel(
    int* __restrict__ counts,   // in: histogram, out: cursor (= offsets[0..N))
    int* __restrict__ offsets)
{
    __shared__ int wave_sums[16];
    const int t    = threadIdx.x;
    const int lane = t & 63;
    const int wid  = t >> 6;
    const int base = t * PER;

    // per-thread sum of its run
    int s = 0;
    for (int i = 0; i < PER; ++i) {
        int j = base + i;
        if (j < N_NODES) s += counts[j];
    }
    // wave-inclusive scan of per-thread sums
    int incl = s;
    for (int off = 1; off < 64; off <<= 1) {
        int u = __shfl_up(incl, off);
        if (lane >= off) incl += u;
    }
    if (lane == 63) wave_sums[wid] = incl;
    __syncthreads();
    if (wid == 0) {
        int v  = (lane < 16) ? wave_sums[lane] : 0;
        int vi = v;
        for (int off = 1; off < 16; off <<= 1) {
            int u = __shfl_up(vi, off);
            if (lane >= off) vi += u;
        }
        if (lane < 16) wave_sums[lane] = vi - v;   // exclusive wave prefix
    }
    __syncthreads();

    int o = wave_sums[wid] + (incl - s);   // exclusive prefix for this thread
    for (int i = 0; i < PER; ++i) {
        int j = base + i;
        if (j < N_NODES) {
            int cnt   = counts[j];
            counts[j] = o;        // cursor init (in place)
            offsets[j] = o;
            o += cnt;
        }
    }
    if (t == SCAN_T - 1) offsets[N_NODES] = o;   // == N_EDGES
}

// ---------- Phase 3: scatter edges into CSR order ----------
__global__ __launch_bounds__(256) void scatter_kernel(
    const int* __restrict__ rows, const int* __restrict__ cols,
    const float* __restrict__ vals, int* __restrict__ cursor,
    int2* __restrict__ edges)
{
    int e = blockIdx.x * 256 + threadIdx.x;
    if (e >= N_EDGES) return;
    int r = rows[e];
    int p = atomicAdd(&cursor[r], 1);
    int2 cv;
    cv.x = cols[e];
    cv.y = __float_as_int(vals[e]);
    edges[p] = cv;
}

// ---------- Phase 4: pull gather, one wave per node ----------
// Per 16-edge chunk: ONE coalesced int2 load (lanes 0-15 hold the chunk),
// then v_readlane broadcasts (compile-time lane idx -> SGPR col/val) and
// 16 INDEPENDENT x-row loads issued before the FMA chain consumes them.
__global__ __launch_bounds__(256) void gather_kernel(
    const float* __restrict__ x, const int2* __restrict__ edges,
    const int* __restrict__ offsets, const float* __restrict__ ws,
    const int* __restrict__ idx, float* __restrict__ out)
{
    const float w = ws[idx[0]];
    int node = blockIdx.x * 4 + (threadIdx.x >> 6);
    int lane = threadIdx.x & 63;
    if (node >= N_NODES) return;

    const int beg = offsets[node];
    const int end = offsets[node + 1];

    float acc0 = 0.f, acc1 = 0.f;
    for (int base = beg; base < end; base += 16) {
        int le = base + (lane & 15);
        int2 cv = edges[le < end ? le : beg];          // beg is valid when loop runs
        int ci = cv.x;
        int vi = (le < end) ? cv.y : 0;                // masked val = 0.0f
#pragma unroll
        for (int k = 0; k < 16; ++k) {
            int c = __builtin_amdgcn_readlane(ci, k);  // SGPR col
            int v = __builtin_amdgcn_readlane(vi, k);  // SGPR val bits
            float xv = x[(size_t)c * D + lane];
            if (k & 1) acc1 += __int_as_float(v) * xv;
            else       acc0 += __int_as_float(v) * xv;
        }
    }
    out[(size_t)node * D + lane] = w * (acc0 + acc1);
}

extern "C" void kernel_launch(void* const* d_in, const int* in_sizes, int n_in,
                              void* d_out, int out_size, void* d_ws, size_t ws_size,
                              hipStream_t stream) {
    const float* x    = (const float*)d_in[0];
    const int*   rows = (const int*)d_in[1];
    const int*   cols = (const int*)d_in[2];
    const float* vals = (const float*)d_in[3];
    const float* ws   = (const float*)d_in[4];
    const int*   idx  = (const int*)d_in[5];
    float*       out  = (float*)d_out;

    // ws layout: [edges: E*8B][offsets: (N+1)*4B][counts/cursor: N*4B]
    const size_t edges_bytes   = (size_t)N_EDGES * sizeof(int2);
    const size_t offsets_bytes = (size_t)(N_NODES + 1) * sizeof(int);
    const size_t counts_bytes  = (size_t)N_NODES * sizeof(int);

    char* wsb = (char*)d_ws;
    int2* edges   = (int2*)wsb;
    int*  offsets = (int*)(wsb + edges_bytes);
    int*  counts  = (int*)(wsb + edges_bytes + offsets_bytes);  // becomes cursor

    hipMemsetAsync(counts, 0, counts_bytes, stream);

    hist_kernel<<<dim3((N_EDGES + 255) / 256), dim3(256), 0, stream>>>(rows, counts);

    scan_kernel<<<dim3(1), dim3(SCAN_T), 0, stream>>>(counts, offsets);

    scatter_kernel<<<dim3((N_EDGES + 255) / 256), dim3(256), 0, stream>>>(
        rows, cols, vals, counts, edges);

    gather_kernel<<<dim3((N_NODES + 3) / 4), dim3(256), 0, stream>>>(
        x, edges, offsets, ws, idx, out);
}

// Round 4
// 131.656 us; speedup vs baseline: 1.8909x; 1.8909x over previous
//
#include <hip/hip_runtime.h>

#define N_NODES 50000
#define N_EDGES 800000
#define D 64
#define NB ((N_NODES + 255) / 256)   // 196 scan blocks

// ---------- Phase 1: histogram of rows ----------
__global__ __launch_bounds__(256) void hist_kernel(
    const int* __restrict__ rows, int* __restrict__ counts)
{
    int e = blockIdx.x * 256 + threadIdx.x;
    if (e < N_EDGES) atomicAdd(&counts[rows[e]], 1);
}

// ---------- Phase 2a: per-block sums (coalesced, parallel) ----------
__global__ __launch_bounds__(256) void scan_blocksum(
    const int* __restrict__ counts, int* __restrict__ bsums)
{
    int j = blockIdx.x * 256 + threadIdx.x;
    int v = (j < N_NODES) ? counts[j] : 0;
    // wave reduce
    for (int off = 32; off > 0; off >>= 1) v += __shfl_down(v, off);
    __shared__ int wsum[4];
    int lane = threadIdx.x & 63, wid = threadIdx.x >> 6;
    if (lane == 0) wsum[wid] = v;
    __syncthreads();
    if (threadIdx.x == 0)
        bsums[blockIdx.x] = wsum[0] + wsum[1] + wsum[2] + wsum[3];
}

// ---------- Phase 2b: scan the 196 block sums in place ----------
__global__ __launch_bounds__(256) void scan_toplevel(
    int* __restrict__ bsums, int* __restrict__ offsets)
{
    const int t = threadIdx.x, lane = t & 63, wid = t >> 6;
    __shared__ int wsum[4];
    int v = (t < NB) ? bsums[t] : 0;
    int incl = v;
    for (int off = 1; off < 64; off <<= 1) {
        int u = __shfl_up(incl, off);
        if (lane >= off) incl += u;
    }
    if (lane == 63) wsum[wid] = incl;
    __syncthreads();
    if (t == 0) {
        int r = 0;
        for (int i = 0; i < 4; ++i) { int s = wsum[i]; wsum[i] = r; r += s; }
    }
    __syncthreads();
    int excl = wsum[wid] + incl - v;
    if (t < NB) bsums[t] = excl;
    if (t == 0) offsets[N_NODES] = N_EDGES;
}

// ---------- Phase 2c: downsweep — write offsets, init cursor in place ----------
__global__ __launch_bounds__(256) void scan_downsweep(
    int* __restrict__ counts,            // in: histogram, out: cursor
    const int* __restrict__ bsums,
    int* __restrict__ offsets)
{
    const int t = threadIdx.x, lane = t & 63, wid = t >> 6;
    int j = blockIdx.x * 256 + t;
    __shared__ int wsum[4];
    int v = (j < N_NODES) ? counts[j] : 0;
    int incl = v;
    for (int off = 1; off < 64; off <<= 1) {
        int u = __shfl_up(incl, off);
        if (lane >= off) incl += u;
    }
    if (lane == 63) wsum[wid] = incl;
    __syncthreads();
    if (t == 0) {
        int r = 0;
        for (int i = 0; i < 4; ++i) { int s = wsum[i]; wsum[i] = r; r += s; }
    }
    __syncthreads();
    int o = bsums[blockIdx.x] + wsum[wid] + (incl - v);
    if (j < N_NODES) {
        offsets[j] = o;
        counts[j]  = o;   // cursor init
    }
}

// ---------- Phase 3: scatter edges into CSR order ----------
__global__ __launch_bounds__(256) void scatter_kernel(
    const int* __restrict__ rows, const int* __restrict__ cols,
    const float* __restrict__ vals, int* __restrict__ cursor,
    int2* __restrict__ edges)
{
    int e = blockIdx.x * 256 + threadIdx.x;
    if (e >= N_EDGES) return;
    int r = rows[e];
    int p = atomicAdd(&cursor[r], 1);
    int2 cv;
    cv.x = cols[e];
    cv.y = __float_as_int(vals[e]);
    edges[p] = cv;
}

// ---------- Phase 4: pull gather, one wave per node ----------
__global__ __launch_bounds__(256) void gather_kernel(
    const float* __restrict__ x, const int2* __restrict__ edges,
    const int* __restrict__ offsets, const float* __restrict__ ws,
    const int* __restrict__ idx, float* __restrict__ out)
{
    const float w = ws[idx[0]];
    int node = blockIdx.x * 4 + (threadIdx.x >> 6);
    int lane = threadIdx.x & 63;
    if (node >= N_NODES) return;

    const int beg = offsets[node];
    const int end = offsets[node + 1];

    float acc0 = 0.f, acc1 = 0.f;
    for (int base = beg; base < end; base += 16) {
        int le = base + (lane & 15);
        int2 cv = edges[le < end ? le : beg];
        int ci = cv.x;
        int vi = (le < end) ? cv.y : 0;
#pragma unroll
        for (int k = 0; k < 16; ++k) {
            int c = __builtin_amdgcn_readlane(ci, k);
            int v = __builtin_amdgcn_readlane(vi, k);
            float xv = x[(size_t)c * D + lane];
            if (k & 1) acc1 += __int_as_float(v) * xv;
            else       acc0 += __int_as_float(v) * xv;
        }
    }
    out[(size_t)node * D + lane] = w * (acc0 + acc1);
}

extern "C" void kernel_launch(void* const* d_in, const int* in_sizes, int n_in,
                              void* d_out, int out_size, void* d_ws, size_t ws_size,
                              hipStream_t stream) {
    const float* x    = (const float*)d_in[0];
    const int*   rows = (const int*)d_in[1];
    const int*   cols = (const int*)d_in[2];
    const float* vals = (const float*)d_in[3];
    const float* ws   = (const float*)d_in[4];
    const int*   idx  = (const int*)d_in[5];
    float*       out  = (float*)d_out;

    // ws layout: [edges: E*8B][offsets: (N+1)*4B][counts/cursor: N*4B][bsums: NB*4B]
    const size_t edges_bytes   = (size_t)N_EDGES * sizeof(int2);
    const size_t offsets_bytes = (size_t)(N_NODES + 1) * sizeof(int);
    const size_t counts_bytes  = (size_t)N_NODES * sizeof(int);

    char* wsb = (char*)d_ws;
    int2* edges   = (int2*)wsb;
    int*  offsets = (int*)(wsb + edges_bytes);
    int*  counts  = (int*)(wsb + edges_bytes + offsets_bytes);
    int*  bsums   = (int*)(wsb + edges_bytes + offsets_bytes + counts_bytes);

    hipMemsetAsync(counts, 0, counts_bytes, stream);

    hist_kernel<<<dim3((N_EDGES + 255) / 256), dim3(256), 0, stream>>>(rows, counts);

    scan_blocksum<<<dim3(NB), dim3(256), 0, stream>>>(counts, bsums);
    scan_toplevel<<<dim3(1), dim3(256), 0, stream>>>(bsums, offsets);
    scan_downsweep<<<dim3(NB), dim3(256), 0, stream>>>(counts, bsums, offsets);

    scatter_kernel<<<dim3((N_EDGES + 255) / 256), dim3(256), 0, stream>>>(
        rows, cols, vals, counts, edges);

    gather_kernel<<<dim3((N_NODES + 3) / 4), dim3(256), 0, stream>>>(
        x, edges, offsets, ws, idx, out);
}

// Round 5
// 122.207 us; speedup vs baseline: 2.0371x; 1.0773x over previous
//
#include <hip/hip_runtime.h>

#define N_NODES 50000
#define N_EDGES 800000
#define D 64
#define NB ((N_NODES + 255) / 256)       // 196 scan blocks

#define N_RANGES 8                        // one row-range per XCD
#define ROWS_PER_RANGE 6250               // 50000 / 8
#define SC_CHUNKS 256                     // edge chunks per range
#define SC_BLK (N_RANGES * SC_CHUNKS)     // 2048 blocks
#define SC_CHUNK_E ((N_EDGES + SC_CHUNKS - 1) / SC_CHUNKS)  // 3125

// ---------- Phase 1: histogram of rows, XCD-range-filtered ----------
// Block b: row-range (b&7) [= its XCD under round-robin], edge chunk (b>>3).
// Each XCD atomics only into its own 25KB slice of counts -> L2-local.
__global__ __launch_bounds__(256) void hist_kernel(
    const int* __restrict__ rows, int* __restrict__ counts)
{
    const int range = blockIdx.x & (N_RANGES - 1);
    const int chunk = blockIdx.x >> 3;
    const int r0 = range * ROWS_PER_RANGE;
    const int r1 = r0 + ROWS_PER_RANGE;
    const int e0 = chunk * SC_CHUNK_E;
    const int e1 = min(e0 + SC_CHUNK_E, N_EDGES);
    for (int e = e0 + threadIdx.x; e < e1; e += 256) {
        int r = rows[e];
        if (r >= r0 && r < r1) atomicAdd(&counts[r], 1);
    }
}

// ---------- Phase 2a: per-block sums ----------
__global__ __launch_bounds__(256) void scan_blocksum(
    const int* __restrict__ counts, int* __restrict__ bsums)
{
    int j = blockIdx.x * 256 + threadIdx.x;
    int v = (j < N_NODES) ? counts[j] : 0;
    for (int off = 32; off > 0; off >>= 1) v += __shfl_down(v, off);
    __shared__ int wsum[4];
    int lane = threadIdx.x & 63, wid = threadIdx.x >> 6;
    if (lane == 0) wsum[wid] = v;
    __syncthreads();
    if (threadIdx.x == 0)
        bsums[blockIdx.x] = wsum[0] + wsum[1] + wsum[2] + wsum[3];
}

// ---------- Phase 2b: scan the 196 block sums in place ----------
__global__ __launch_bounds__(256) void scan_toplevel(
    int* __restrict__ bsums, int* __restrict__ offsets)
{
    const int t = threadIdx.x, lane = t & 63, wid = t >> 6;
    __shared__ int wsum[4];
    int v = (t < NB) ? bsums[t] : 0;
    int incl = v;
    for (int off = 1; off < 64; off <<= 1) {
        int u = __shfl_up(incl, off);
        if (lane >= off) incl += u;
    }
    if (lane == 63) wsum[wid] = incl;
    __syncthreads();
    if (t == 0) {
        int r = 0;
        for (int i = 0; i < 4; ++i) { int s = wsum[i]; wsum[i] = r; r += s; }
    }
    __syncthreads();
    int excl = wsum[wid] + incl - v;
    if (t < NB) bsums[t] = excl;
    if (t == 0) offsets[N_NODES] = N_EDGES;
}

// ---------- Phase 2c: downsweep — write offsets, init cursor ----------
__global__ __launch_bounds__(256) void scan_downsweep(
    int* __restrict__ counts,            // in: histogram, out: cursor
    const int* __restrict__ bsums,
    int* __restrict__ offsets)
{
    const int t = threadIdx.x, lane = t & 63, wid = t >> 6;
    int j = blockIdx.x * 256 + t;
    __shared__ int wsum[4];
    int v = (j < N_NODES) ? counts[j] : 0;
    int incl = v;
    for (int off = 1; off < 64; off <<= 1) {
        int u = __shfl_up(incl, off);
        if (lane >= off) incl += u;
    }
    if (lane == 63) wsum[wid] = incl;
    __syncthreads();
    if (t == 0) {
        int r = 0;
        for (int i = 0; i < 4; ++i) { int s = wsum[i]; wsum[i] = r; r += s; }
    }
    __syncthreads();
    int o = bsums[blockIdx.x] + wsum[wid] + (incl - v);
    if (j < N_NODES) {
        offsets[j] = o;
        counts[j]  = o;   // cursor init
    }
}

// ---------- Phase 3: scatter edges into CSR order, XCD-range-filtered ----------
// Row-range i's destination window [offsets[r0], offsets[r1]) is written by
// only one XCD -> lines merge in that XCD's L2 -> ~clean full-line writebacks.
__global__ __launch_bounds__(256) void scatter_kernel(
    const int* __restrict__ rows, const int* __restrict__ cols,
    const float* __restrict__ vals, int* __restrict__ cursor,
    int2* __restrict__ edges)
{
    const int range = blockIdx.x & (N_RANGES - 1);
    const int chunk = blockIdx.x >> 3;
    const int r0 = range * ROWS_PER_RANGE;
    const int r1 = r0 + ROWS_PER_RANGE;
    const int e0 = chunk * SC_CHUNK_E;
    const int e1 = min(e0 + SC_CHUNK_E, N_EDGES);
    for (int e = e0 + threadIdx.x; e < e1; e += 256) {
        int r = rows[e];
        if (r >= r0 && r < r1) {
            int p = atomicAdd(&cursor[r], 1);
            int2 cv;
            cv.x = cols[e];
            cv.y = __float_as_int(vals[e]);
            edges[p] = cv;
        }
    }
}

// ---------- Phase 4: pull gather, one wave per node, XCD-aligned ----------
// Block b covers nodes in row-range (b&7): node-range i runs on the XCD whose
// L2 just produced edges window i. 8 * 1563 = 12504 blocks, 4 nodes each.
#define GB_PER_RANGE ((ROWS_PER_RANGE + 3) / 4)   // 1563

__global__ __launch_bounds__(256) void gather_kernel(
    const float* __restrict__ x, const int2* __restrict__ edges,
    const int* __restrict__ offsets, const float* __restrict__ ws,
    const int* __restrict__ idx, float* __restrict__ out)
{
    const float w = ws[idx[0]];
    const int range = blockIdx.x & (N_RANGES - 1);
    const int j     = blockIdx.x >> 3;
    const int local = j * 4 + (threadIdx.x >> 6);
    if (local >= ROWS_PER_RANGE) return;
    const int node = range * ROWS_PER_RANGE + local;
    const int lane = threadIdx.x & 63;

    const int beg = offsets[node];
    const int end = offsets[node + 1];

    float acc0 = 0.f, acc1 = 0.f;
    for (int base = beg; base < end; base += 16) {
        int le = base + (lane & 15);
        int2 cv = edges[le < end ? le : beg];
        int ci = cv.x;
        int vi = (le < end) ? cv.y : 0;
#pragma unroll
        for (int k = 0; k < 16; ++k) {
            int c = __builtin_amdgcn_readlane(ci, k);
            int v = __builtin_amdgcn_readlane(vi, k);
            float xv = x[(size_t)c * D + lane];
            if (k & 1) acc1 += __int_as_float(v) * xv;
            else       acc0 += __int_as_float(v) * xv;
        }
    }
    out[(size_t)node * D + lane] = w * (acc0 + acc1);
}

extern "C" void kernel_launch(void* const* d_in, const int* in_sizes, int n_in,
                              void* d_out, int out_size, void* d_ws, size_t ws_size,
                              hipStream_t stream) {
    const float* x    = (const float*)d_in[0];
    const int*   rows = (const int*)d_in[1];
    const int*   cols = (const int*)d_in[2];
    const float* vals = (const float*)d_in[3];
    const float* ws   = (const float*)d_in[4];
    const int*   idx  = (const int*)d_in[5];
    float*       out  = (float*)d_out;

    // ws layout: [edges: E*8B][offsets: (N+1)*4B][counts/cursor: N*4B][bsums: NB*4B]
    const size_t edges_bytes   = (size_t)N_EDGES * sizeof(int2);
    const size_t offsets_bytes = (size_t)(N_NODES + 1) * sizeof(int);
    const size_t counts_bytes  = (size_t)N_NODES * sizeof(int);

    char* wsb = (char*)d_ws;
    int2* edges   = (int2*)wsb;
    int*  offsets = (int*)(wsb + edges_bytes);
    int*  counts  = (int*)(wsb + edges_bytes + offsets_bytes);
    int*  bsums   = (int*)(wsb + edges_bytes + offsets_bytes + counts_bytes);

    hipMemsetAsync(counts, 0, counts_bytes, stream);

    hist_kernel<<<dim3(SC_BLK), dim3(256), 0, stream>>>(rows, counts);

    scan_blocksum<<<dim3(NB), dim3(256), 0, stream>>>(counts, bsums);
    scan_toplevel<<<dim3(1), dim3(256), 0, stream>>>(bsums, offsets);
    scan_downsweep<<<dim3(NB), dim3(256), 0, stream>>>(counts, bsums, offsets);

    scatter_kernel<<<dim3(SC_BLK), dim3(256), 0, stream>>>(
        rows, cols, vals, counts, edges);

    gather_kernel<<<dim3(N_RANGES * GB_PER_RANGE), dim3(256), 0, stream>>>(
        x, edges, offsets, ws, idx, out);
}